// Round 8
// baseline (127.927 us; speedup 1.0000x reference)
//
#include <hip/hip_runtime.h>
#include <math.h>

#define N_TOTAL 8192
#define BHALF   4096
#define KDIM    128
#define NT64    128                          // 8192 / 64
#define NBLK    (NT64 * (NT64 + 1) / 2)      // 8256 triangular 64x64 tiles

typedef __bf16 bf16x8 __attribute__((ext_vector_type(8)));
typedef __bf16 bf16x2 __attribute__((ext_vector_type(2)));
typedef float  f32x4  __attribute__((ext_vector_type(4)));

// ---------------------------------------------------------------------------
// Kernel A (fused prep+pos): one wave per pair (i, i+BHALF).
//  hsq[i] = 0.5 + ||x_i||^2  (so pairwise denom = hsq_i + hsq_j - 2*dot),
//  bf16 copy of both rows, zero T, per-block pos partial (plain store).
// ---------------------------------------------------------------------------
__global__ __launch_bounds__(256) void k_prep_pos(const float* __restrict__ F,
                                                  __bf16* __restrict__ Fbf,
                                                  float* __restrict__ hsq,
                                                  float* __restrict__ T,
                                                  float* __restrict__ posPart) {
    int t = threadIdx.x;
    int w = t >> 6, l = t & 63;
    int p = blockIdx.x * 4 + w;          // pair index 0..4095
    const float2* r1 = (const float2*)(F + (size_t)p * KDIM);
    const float2* r2 = (const float2*)(F + (size_t)(p + BHALF) * KDIM);
    float2 a = r1[l];
    float2 c = r2[l];

    float s1 = fmaf(a.x, a.x, a.y * a.y);
    float s2 = fmaf(c.x, c.x, c.y * c.y);
    float dp = fmaf(a.x, c.x, a.y * c.y);
#pragma unroll
    for (int off = 32; off > 0; off >>= 1) {
        s1 += __shfl_down(s1, off);
        s2 += __shfl_down(s2, off);
        dp += __shfl_down(dp, off);
    }

    bf16x2 pa, pc;
    pa[0] = (__bf16)a.x; pa[1] = (__bf16)a.y;
    pc[0] = (__bf16)c.x; pc[1] = (__bf16)c.y;
    ((bf16x2*)(Fbf + (size_t)p * KDIM))[l] = pa;
    ((bf16x2*)(Fbf + (size_t)(p + BHALF) * KDIM))[l] = pc;

    __shared__ float posRed[4];
    if (l == 0) {
        hsq[p] = 0.5f + s1;
        hsq[p + BHALF] = 0.5f + s2;
        T[p] = 0.0f;
        T[p + BHALF] = 0.0f;
        float d2 = fmaxf(s1 + s2 - 2.0f * dp, 0.0f);
        posRed[w] = logf(1.0f + d2);
    }
    __syncthreads();
    if (t == 0)
        posPart[blockIdx.x] = posRed[0] + posRed[1] + posRed[2] + posRed[3];
}

// ---------------------------------------------------------------------------
// Kernel B: MFMA pairwise Cauchy row/col sums — 64x64 tiles, 2x2 fragments
// per wave (acc = 16 VGPRs, total ~90 -> ~20 waves/CU occupancy; the
// element-wise Cauchy epilogue is the measured floor and needs TLP to hide
// rcp/mem latency). No LDS staging (Fbf L2-resident); fragment loads straight
// from global. Per-entry epilogue minimized: denom = hsq_i + hsq_j - 2*acc
// (add + fma + rcp + 2 adds; no fmax — denom >= ~0.94 guaranteed).
// 8256 triangular tiles; strict-upper mask on diagonal tiles; T excludes
// diagonal (final uses log(T)).
// ---------------------------------------------------------------------------
__global__ __launch_bounds__(256) void k_pairwise(
        const __bf16* __restrict__ Fbf,
        const float* __restrict__ hsq,
        float* __restrict__ T) {
    // triangular decode: block b -> (ti, tj), tj >= ti, 128x128 tile grid
    int b = blockIdx.x;
    int ti = (int)((257.0f - sqrtf(66049.0f - 8.0f * (float)b)) * 0.5f);
    while (ti * (257 - ti) / 2 > b) --ti;
    while ((ti + 1) * (256 - ti) / 2 <= b) ++ti;
    int tj = ti + (b - ti * (257 - ti) / 2);
    int I = ti * 64, J = tj * 64;
    bool diag = (ti == tj);

    __shared__ float rowAcc[64][2];
    __shared__ float colAcc[64][2];

    int t = threadIdx.x;
    int w = t >> 6;               // wave 0..3
    int l = t & 63;
    int wr = w >> 1, wc = w & 1;  // 2x2 wave grid, 32x32 quadrant each
    int low = l & 15, kb = l >> 4;

    const bf16x8* Fg = (const bf16x8*)Fbf;   // granule-indexed: row*16 + g

    // ---- K-loop: 4 steps of K=32, 2x2 fragments straight from L2 ----
    f32x4 acc[2][2] = {};
#pragma unroll
    for (int s = 0; s < 4; ++s) {
        int g = s * 4 + kb;
        bf16x8 aF[2], bF[2];
#pragma unroll
        for (int fr = 0; fr < 2; ++fr)
            aF[fr] = Fg[(size_t)(I + wr * 32 + fr * 16 + low) * 16 + g];
#pragma unroll
        for (int fc = 0; fc < 2; ++fc)
            bF[fc] = Fg[(size_t)(J + wc * 32 + fc * 16 + low) * 16 + g];
#pragma unroll
        for (int fr = 0; fr < 2; ++fr)
#pragma unroll
            for (int fc = 0; fc < 2; ++fc)
                acc[fr][fc] = __builtin_amdgcn_mfma_f32_16x16x32_bf16(
                    aF[fr], bF[fc], acc[fr][fc], 0, 0, 0);
    }

    // ---- epilogue: Cauchy + row/col partial sums ----
    // C/D layout: col = low, row = kb*4 + reg (within each 16x16 fragment)
    float hi[2][4], hj[2];
#pragma unroll
    for (int fr = 0; fr < 2; ++fr)
#pragma unroll
        for (int r = 0; r < 4; ++r)
            hi[fr][r] = hsq[I + wr * 32 + fr * 16 + kb * 4 + r];
#pragma unroll
    for (int fc = 0; fc < 2; ++fc)
        hj[fc] = hsq[J + wc * 32 + fc * 16 + low];

    float rowPart[2][4] = {};
    float colPart[2] = {0.f, 0.f};
#define EPI(MASK)                                                              \
    _Pragma("unroll")                                                          \
    for (int fr = 0; fr < 2; ++fr) {                                           \
        _Pragma("unroll")                                                      \
        for (int fc = 0; fc < 2; ++fc) {                                       \
            _Pragma("unroll")                                                  \
            for (int r = 0; r < 4; ++r) {                                      \
                float den = fmaf(-2.0f, acc[fr][fc][r], hi[fr][r] + hj[fc]);   \
                float v = __builtin_amdgcn_rcpf(den);                          \
                if (MASK) {                                                    \
                    int R = wr * 32 + fr * 16 + kb * 4 + r;                    \
                    int C = wc * 32 + fc * 16 + low;                           \
                    v = (C > R) ? v : 0.0f;   /* strict upper on diag tile */  \
                }                                                              \
                rowPart[fr][r] += v;                                           \
                colPart[fc] += v;                                              \
            }                                                                  \
        }                                                                      \
    }
    if (diag) { EPI(true) } else { EPI(false) }
#undef EPI

    // row partials: reduce across the 16 lanes sharing a row (low)
#pragma unroll
    for (int fr = 0; fr < 2; ++fr)
#pragma unroll
        for (int r = 0; r < 4; ++r) {
            float x = rowPart[fr][r];
            x += __shfl_xor(x, 1);
            x += __shfl_xor(x, 2);
            x += __shfl_xor(x, 4);
            x += __shfl_xor(x, 8);
            if (low == 0)
                rowAcc[wr * 32 + fr * 16 + kb * 4 + r][wc] = x;
        }

    // col partials: reduce across the 4 lane-quads (kb)
#pragma unroll
    for (int fc = 0; fc < 2; ++fc) {
        float x = colPart[fc];
        x += __shfl_xor(x, 16);
        x += __shfl_xor(x, 32);
        if (kb == 0)
            colAcc[wc * 32 + fc * 16 + low][wr] = x;
    }
    __syncthreads();

    // scatter: row sums to T[I+..], mirrored col sums to T[J+..]
    if (t < 64) {
        atomicAdd(&T[I + t], rowAcc[t][0] + rowAcc[t][1]);
    } else if (t < 128) {
        int c = t - 64;
        atomicAdd(&T[J + c], colAcc[c][0] + colAcc[c][1]);
    }
}

// ---------------------------------------------------------------------------
// Kernel C: final scalar, one 1024-thread block, plain store (no memset).
// T excludes the diagonal -> loss = [sum 0.5*log(T_i) + sum posPart] / b.
// ---------------------------------------------------------------------------
__global__ __launch_bounds__(1024) void k_final(const float* __restrict__ T,
                                                const float* __restrict__ posPart,
                                                float* __restrict__ out) {
    int t = threadIdx.x;
    float s = 0.0f;
    for (int i = t; i < N_TOTAL; i += 1024) s += logf(T[i]);
    s *= 0.5f;
    for (int i = t; i < 1024; i += 1024) s += posPart[i];
#pragma unroll
    for (int off = 32; off > 0; off >>= 1) s += __shfl_down(s, off);
    __shared__ float red[16];
    int w = t >> 6, l = t & 63;
    if (l == 0) red[w] = s;
    __syncthreads();
    if (t == 0) {
        float S = 0.0f;
#pragma unroll
        for (int i = 0; i < 16; ++i) S += red[i];
        out[0] = S / (float)BHALF;
    }
}

// ---------------------------------------------------------------------------
extern "C" void kernel_launch(void* const* d_in, const int* in_sizes, int n_in,
                              void* d_out, int out_size, void* d_ws, size_t ws_size,
                              hipStream_t stream) {
    const float* F = (const float*)d_in[0];
    float* out = (float*)d_out;

    char* ws = (char*)d_ws;
    __bf16* Fbf     = (__bf16*)ws;                                // 2 MB
    float*  hsq     = (float*)(ws + (size_t)N_TOTAL * KDIM * 2);  // 8192 f
    float*  T       = hsq + N_TOTAL;                              // 8192 f
    float*  posPart = T + N_TOTAL;                                // 1024 f

    k_prep_pos<<<BHALF / 4, 256, 0, stream>>>(F, Fbf, hsq, T, posPart);
    k_pairwise<<<NBLK, 256, 0, stream>>>(Fbf, hsq, T);
    k_final<<<1, 1024, 0, stream>>>(T, posPart, out);
}